// Round 7
// baseline (25654.813 us; speedup 1.0000x reference)
//
#include <hip/hip_runtime.h>
#include <hip/hip_bf16.h>

#define NN_NODES 100000
#define NN_PAD   100032
#define NN_EDGES 600000
#define CC 128
#define NL 3
#define NS 10

typedef __attribute__((ext_vector_type(8))) short s16x8;
typedef __attribute__((ext_vector_type(4))) float f32x4;

__device__ __forceinline__ ushort f2bf(float f) {
    union { float f; unsigned u; } v; v.f = f;
    unsigned r = (v.u + 0x7FFFu + ((v.u >> 16) & 1u)) >> 16;
    return (ushort)r;
}
__device__ __forceinline__ float bf2f(ushort u) {
    union { unsigned u; float f; } v; v.u = ((unsigned)u) << 16;
    return v.f;
}
// fp32 -> 3 bf16 planes (v ~= p1 + p2 + p3, residual ~2^-27 rel)
__device__ __forceinline__ void split3(float v, ushort& p1, ushort& p2, ushort& p3) {
    ushort t1 = f2bf(v); float f1 = bf2f(t1);
    float r1 = v - f1;
    ushort t2 = f2bf(r1); float f2 = bf2f(t2);
    ushort t3 = f2bf(r1 - f2);
    p1 = t1; p2 = t2; p3 = t3;
}

// ---------------- CSR build ----------------

__global__ __launch_bounds__(256) void count_deg(const int* __restrict__ dst,
                                                 int* __restrict__ deg) {
    int e = blockIdx.x * 256 + threadIdx.x;
    if (e < NN_EDGES) atomicAdd(&deg[dst[e]], 1);
}

__global__ __launch_bounds__(256) void scan1(const int* __restrict__ deg,
                                             int* __restrict__ out,
                                             int* __restrict__ partials) {
    __shared__ int lds[256];
    int t = threadIdx.x, b = blockIdx.x;
    int base = b * 1024 + t * 4;
    int v[4];
    int tsum = 0;
#pragma unroll
    for (int i = 0; i < 4; i++) {
        int idx = base + i;
        v[i] = (idx < NN_NODES) ? deg[idx] : 0;
        tsum += v[i];
    }
    lds[t] = tsum;
    __syncthreads();
    for (int off = 1; off < 256; off <<= 1) {
        int xv = (t >= off) ? lds[t - off] : 0;
        __syncthreads();
        lds[t] += xv;
        __syncthreads();
    }
    int run = lds[t] - tsum;
    if (t == 255) partials[b] = lds[255];
#pragma unroll
    for (int i = 0; i < 4; i++) {
        int idx = base + i;
        if (idx < NN_NODES) out[idx] = run;
        run += v[i];
    }
}

__global__ __launch_bounds__(128) void scan2(int* __restrict__ partials) {
    __shared__ int lds[128];
    int t = threadIdx.x;
    int v = (t < 98) ? partials[t] : 0;
    lds[t] = v;
    __syncthreads();
    for (int off = 1; off < 128; off <<= 1) {
        int xv = (t >= off) ? lds[t - off] : 0;
        __syncthreads();
        lds[t] += xv;
        __syncthreads();
    }
    if (t < 98) partials[t] = lds[t] - v;
    if (t == 127) partials[98] = lds[127];
}

__global__ __launch_bounds__(256) void scan3(int* __restrict__ offsets,
                                             const int* __restrict__ partials) {
    int b = blockIdx.x;
    int add = partials[b];
    int base = b * 1024 + threadIdx.x * 4;
#pragma unroll
    for (int i = 0; i < 4; i++) {
        int idx = base + i;
        if (idx < NN_NODES) offsets[idx] += add;
    }
    if (b == 0 && threadIdx.x == 0) offsets[NN_NODES] = partials[98];
}

__global__ __launch_bounds__(256) void fill_csr(const int* __restrict__ src,
                                                const int* __restrict__ dst,
                                                const int* __restrict__ offs,
                                                int* __restrict__ cursor,
                                                int* __restrict__ csr) {
    int e = blockIdx.x * 256 + threadIdx.x;
    if (e < NN_EDGES) {
        int d = dst[e];
        int pos = atomicAdd(&cursor[d], 1);
        csr[offs[d] + pos] = src[e];
    }
}

// ---------------- weight packing: bf16x3 planes in B-fragment order ----------------
#define WM_LS (3 * 4 * 8 * 512)

__global__ __launch_bounds__(256) void pack_wm3(const float* __restrict__ w,
                                                ushort* __restrict__ wm3) {
    int idx = blockIdx.x * 256 + threadIdx.x;   // (ls,ks,nt,lane): 30*4*8*64
    if (idx >= NL * NS * 4 * 8 * 64) return;
    int lane = idx & 63, nt = (idx >> 6) & 7, ks = (idx >> 9) & 3, ls = idx >> 11;
    int lr = lane & 15, kg = lane >> 4;
    int k0 = ks * 32 + kg * 8, col = nt * 16 + lr;
    const float* W = w + (size_t)ls * CC * CC;
    ushort o1[8], o2[8], o3[8];
#pragma unroll
    for (int i = 0; i < 8; i++) split3(W[(size_t)(k0 + i) * CC + col], o1[i], o2[i], o3[i]);
    size_t base = (size_t)ls * WM_LS;
    *(s16x8*)&wm3[base + ((size_t)((0 * 4 + ks) * 8 + nt)) * 512 + lane * 8] = *(s16x8*)o1;
    *(s16x8*)&wm3[base + ((size_t)((1 * 4 + ks) * 8 + nt)) * 512 + lane * 8] = *(s16x8*)o2;
    *(s16x8*)&wm3[base + ((size_t)((2 * 4 + ks) * 8 + nt)) * 512 + lane * 8] = *(s16x8*)o3;
}

#define GW_ML (3 * 4 * 24 * 512)

__global__ __launch_bounds__(256) void pack_gw3(const float* __restrict__ wih,
                                                const float* __restrict__ whh,
                                                ushort* __restrict__ gw3) {
    int idx = blockIdx.x * 256 + threadIdx.x;   // ((ml*4+ks)*24+tile)*64+lane : 6*4*24*64
    if (idx >= 6 * 4 * 24 * 64) return;
    int lane = idx & 63;
    int t = idx >> 6;
    int tile = t % 24;
    int q = t / 24;
    int ks = q & 3, ml = q >> 2;
    int mat = ml / NL, l = ml % NL;
    int lr = lane & 15, kg = lane >> 4;
    const float* src = (mat ? whh : wih) + (size_t)l * 384 * CC;
    int row = tile * 16 + lr, k0 = ks * 32 + kg * 8;
    ushort o1[8], o2[8], o3[8];
#pragma unroll
    for (int i = 0; i < 8; i++) split3(src[(size_t)row * CC + k0 + i], o1[i], o2[i], o3[i]);
    size_t base = (size_t)ml * GW_ML;
    *(s16x8*)&gw3[base + ((size_t)((0 * 4 + ks) * 24 + tile)) * 512 + lane * 8] = *(s16x8*)o1;
    *(s16x8*)&gw3[base + ((size_t)((1 * 4 + ks) * 24 + tile)) * 512 + lane * 8] = *(s16x8*)o2;
    *(s16x8*)&gw3[base + ((size_t)((2 * 4 + ks) * 24 + tile)) * 512 + lane * 8] = *(s16x8*)o3;
}

__global__ __launch_bounds__(256) void pack_bias_f32(const float* __restrict__ bih,
                                                     const float* __restrict__ bhh,
                                                     float* __restrict__ bpack) {
    int idx = blockIdx.x * 256 + threadIdx.x;
    if (idx >= NL * 512) return;
    int u = idx & 511, l = idx >> 9;
    int c = u >> 2, g = u & 3;
    const float* bi = bih + (size_t)l * 384;
    const float* bh = bhh + (size_t)l * 384;
    float v;
    if (g == 0)      v = bi[c] + bh[c];
    else if (g == 1) v = bi[128 + c] + bh[128 + c];
    else if (g == 2) v = bi[256 + c];
    else             v = bh[256 + c];
    bpack[idx] = v;
}

// stage 32 fp32 rows -> 3 swizzled bf16 LDS planes (8 KB each)
#define STAGE_PLANES(SRC)                                                   \
    {                                                                       \
        const float4* sg = (const float4*)((SRC) + nbase * CC);             \
        _Pragma("unroll")                                                   \
        for (int i = 0; i < 4; i++) {                                       \
            int fi = tid + i * 256;                                         \
            int row = fi >> 5;                                              \
            float4 v = sg[fi];                                              \
            ushort4 s1, s2, s3;                                             \
            split3(v.x, s1.x, s2.x, s3.x);                                  \
            split3(v.y, s1.y, s2.y, s3.y);                                  \
            split3(v.z, s1.z, s2.z, s3.z);                                  \
            split3(v.w, s1.w, s2.w, s3.w);                                  \
            int boff = row * 256 + ((((fi & 31) * 8)) ^ ((row & 7) << 4));  \
            *(ushort4*)((char*)&Ap[0][0] + boff) = s1;                      \
            *(ushort4*)((char*)&Ap[1][0] + boff) = s2;                      \
            *(ushort4*)((char*)&Ap[2][0] + boff) = s3;                      \
        }                                                                   \
    }

// ---------------- m = h @ W  (bf16x3 MFMA, 32 rows/block, 24 KB LDS) ----------------

__global__ __launch_bounds__(256, 6) void gemm_m_mfma(const float* __restrict__ h,
                                                      const ushort* __restrict__ wm,
                                                      float* __restrict__ m) {
    __shared__ ushort Ap[3][32 * 128];
    int tid = threadIdx.x;
    size_t nbase = (size_t)blockIdx.x * 32;
    STAGE_PLANES(h)
    __syncthreads();
    int wave = tid >> 6, lane = tid & 63, lr = lane & 15, kg = lane >> 4;
    f32x4 acc[2][2] = {};
#pragma unroll
    for (int ks = 0; ks < 4; ks++) {
        s16x8 a[3][2];
#pragma unroll
        for (int p = 0; p < 3; p++)
#pragma unroll
            for (int mt = 0; mt < 2; mt++) {
                int row = mt * 16 + lr;
                int boff = row * 256 + ((ks * 64 + kg * 16) ^ ((row & 7) << 4));
                a[p][mt] = *(const s16x8*)((const char*)&Ap[p][0] + boff);
            }
#pragma unroll
        for (int pb = 0; pb < 3; pb++) {
            s16x8 b0 = *(const s16x8*)&wm[((size_t)((pb * 4 + ks) * 8 + wave * 2)) * 512 + lane * 8];
            s16x8 b1 = *(const s16x8*)&wm[((size_t)((pb * 4 + ks) * 8 + wave * 2 + 1)) * 512 + lane * 8];
            int npa = 3 - pb;
#pragma unroll
            for (int pa = 0; pa < 3; pa++) {
                if (pa < npa) {
#pragma unroll
                    for (int mt = 0; mt < 2; mt++) {
                        acc[mt][0] = __builtin_amdgcn_mfma_f32_16x16x32_bf16(a[pa][mt], b0, acc[mt][0], 0, 0, 0);
                        acc[mt][1] = __builtin_amdgcn_mfma_f32_16x16x32_bf16(a[pa][mt], b1, acc[mt][1], 0, 0, 0);
                    }
                }
            }
        }
    }
#pragma unroll
    for (int mt = 0; mt < 2; mt++)
#pragma unroll
        for (int nt = 0; nt < 2; nt++) {
            int col = (wave * 2 + nt) * 16 + lr;
#pragma unroll
            for (int j = 0; j < 4; j++) {
                size_t row = nbase + mt * 16 + kg * 4 + j;
                m[row * CC + col] = acc[mt][nt][j];
            }
        }
}

// ---------------- agg[n] = sum over in-edges of m[src] (fp32) ----------------

__global__ __launch_bounds__(256) void gather_agg(const float* __restrict__ mbuf,
                                                  const int* __restrict__ offs,
                                                  const int* __restrict__ csr,
                                                  float* __restrict__ agg) {
    int tid = threadIdx.x;
    int node = blockIdx.x * 8 + (tid >> 5);
    int c4 = (tid & 31) << 2;
    int b = offs[node], e = offs[node + 1];
    float ax = 0.f, ay = 0.f, az = 0.f, aw = 0.f;
    for (int j = b; j < e; j++) {
        int s = csr[j];
        float4 v = *(const float4*)&mbuf[(size_t)s * CC + c4];
        ax += v.x; ay += v.y; az += v.z; aw += v.w;
    }
    *(float4*)&agg[(size_t)node * CC + c4] = make_float4(ax, ay, az, aw);
}

// ---------------- fused gates (bf16x3 MFMA, two-phase, 24 KB LDS) ----------------
// Phase 1: stage agg planes -> pass 1 (B = gwi): accR/accZ/accN1
// Phase 2: stage h planes   -> pass 2 (B = gwh): accR/accZ (accumulate) / accN2
// Wave w owns r-tiles {2w,2w+1}, z {8+2w,9+2w}, n {16+2w,17+2w}.

__global__ __launch_bounds__(256, 6) void gates_mfma(const float* __restrict__ agg,
                                                     float* __restrict__ h,
                                                     const ushort* __restrict__ gwi,
                                                     const ushort* __restrict__ gwh,
                                                     const float* __restrict__ bpk,
                                                     int relu) {
    __shared__ ushort Ap[3][32 * 128];
    int tid = threadIdx.x;
    size_t nbase = (size_t)blockIdx.x * 32;
    int wave = tid >> 6, lane = tid & 63, lr = lane & 15, kg = lane >> 4;
    f32x4 accR[2][2] = {}, accZ[2][2] = {}, accN1[2][2] = {}, accN2[2][2] = {};

    // ---------- phase 1: A = agg ----------
    STAGE_PLANES(agg)
    __syncthreads();
#pragma unroll
    for (int ks = 0; ks < 4; ks++) {
        s16x8 aA[3][2];
#pragma unroll
        for (int p = 0; p < 3; p++)
#pragma unroll
            for (int mt = 0; mt < 2; mt++) {
                int row = mt * 16 + lr;
                int boff = row * 256 + ((ks * 64 + kg * 16) ^ ((row & 7) << 4));
                aA[p][mt] = *(const s16x8*)((const char*)&Ap[p][0] + boff);
            }
#pragma unroll
        for (int pb = 0; pb < 3; pb++) {
            size_t cb = ((size_t)(pb * 4 + ks) * 24) * 512 + lane * 8;
            s16x8 br0 = *(const s16x8*)&gwi[cb + (size_t)(2 * wave) * 512];
            s16x8 br1 = *(const s16x8*)&gwi[cb + (size_t)(2 * wave + 1) * 512];
            s16x8 bz0 = *(const s16x8*)&gwi[cb + (size_t)(8 + 2 * wave) * 512];
            s16x8 bz1 = *(const s16x8*)&gwi[cb + (size_t)(9 + 2 * wave) * 512];
            s16x8 bn0 = *(const s16x8*)&gwi[cb + (size_t)(16 + 2 * wave) * 512];
            s16x8 bn1 = *(const s16x8*)&gwi[cb + (size_t)(17 + 2 * wave) * 512];
            int npa = 3 - pb;
#pragma unroll
            for (int pa = 0; pa < 3; pa++) {
                if (pa < npa) {
#pragma unroll
                    for (int mt = 0; mt < 2; mt++) {
                        accR[mt][0] = __builtin_amdgcn_mfma_f32_16x16x32_bf16(aA[pa][mt], br0, accR[mt][0], 0, 0, 0);
                        accR[mt][1] = __builtin_amdgcn_mfma_f32_16x16x32_bf16(aA[pa][mt], br1, accR[mt][1], 0, 0, 0);
                        accZ[mt][0] = __builtin_amdgcn_mfma_f32_16x16x32_bf16(aA[pa][mt], bz0, accZ[mt][0], 0, 0, 0);
                        accZ[mt][1] = __builtin_amdgcn_mfma_f32_16x16x32_bf16(aA[pa][mt], bz1, accZ[mt][1], 0, 0, 0);
                        accN1[mt][0] = __builtin_amdgcn_mfma_f32_16x16x32_bf16(aA[pa][mt], bn0, accN1[mt][0], 0, 0, 0);
                        accN1[mt][1] = __builtin_amdgcn_mfma_f32_16x16x32_bf16(aA[pa][mt], bn1, accN1[mt][1], 0, 0, 0);
                    }
                }
            }
        }
    }
    __syncthreads();   // all phase-1 LDS reads done before overwrite

    // ---------- phase 2: A = h ----------
    STAGE_PLANES(h)
    __syncthreads();
#pragma unroll
    for (int ks = 0; ks < 4; ks++) {
        s16x8 aH[3][2];
#pragma unroll
        for (int p = 0; p < 3; p++)
#pragma unroll
            for (int mt = 0; mt < 2; mt++) {
                int row = mt * 16 + lr;
                int boff = row * 256 + ((ks * 64 + kg * 16) ^ ((row & 7) << 4));
                aH[p][mt] = *(const s16x8*)((const char*)&Ap[p][0] + boff);
            }
#pragma unroll
        for (int pb = 0; pb < 3; pb++) {
            size_t cb = ((size_t)(pb * 4 + ks) * 24) * 512 + lane * 8;
            s16x8 br0 = *(const s16x8*)&gwh[cb + (size_t)(2 * wave) * 512];
            s16x8 br1 = *(const s16x8*)&gwh[cb + (size_t)(2 * wave + 1) * 512];
            s16x8 bz0 = *(const s16x8*)&gwh[cb + (size_t)(8 + 2 * wave) * 512];
            s16x8 bz1 = *(const s16x8*)&gwh[cb + (size_t)(9 + 2 * wave) * 512];
            s16x8 bn0 = *(const s16x8*)&gwh[cb + (size_t)(16 + 2 * wave) * 512];
            s16x8 bn1 = *(const s16x8*)&gwh[cb + (size_t)(17 + 2 * wave) * 512];
            int npa = 3 - pb;
#pragma unroll
            for (int pa = 0; pa < 3; pa++) {
                if (pa < npa) {
#pragma unroll
                    for (int mt = 0; mt < 2; mt++) {
                        accR[mt][0] = __builtin_amdgcn_mfma_f32_16x16x32_bf16(aH[pa][mt], br0, accR[mt][0], 0, 0, 0);
                        accR[mt][1] = __builtin_amdgcn_mfma_f32_16x16x32_bf16(aH[pa][mt], br1, accR[mt][1], 0, 0, 0);
                        accZ[mt][0] = __builtin_amdgcn_mfma_f32_16x16x32_bf16(aH[pa][mt], bz0, accZ[mt][0], 0, 0, 0);
                        accZ[mt][1] = __builtin_amdgcn_mfma_f32_16x16x32_bf16(aH[pa][mt], bz1, accZ[mt][1], 0, 0, 0);
                        accN2[mt][0] = __builtin_amdgcn_mfma_f32_16x16x32_bf16(aH[pa][mt], bn0, accN2[mt][0], 0, 0, 0);
                        accN2[mt][1] = __builtin_amdgcn_mfma_f32_16x16x32_bf16(aH[pa][mt], bn1, accN2[mt][1], 0, 0, 0);
                    }
                }
            }
        }
    }

    // epilogue (identical math to round 6)
#pragma unroll
    for (int mt = 0; mt < 2; mt++)
#pragma unroll
        for (int t = 0; t < 2; t++) {
            int c = 32 * wave + 16 * t + lr;
            float4 bb = *(const float4*)&bpk[c * 4];
#pragma unroll
            for (int j = 0; j < 4; j++) {
                size_t row = nbase + mt * 16 + kg * 4 + j;
                float rr = 1.f / (1.f + expf(-(accR[mt][t][j] + bb.x)));
                float zz = 1.f / (1.f + expf(-(accZ[mt][t][j] + bb.y)));
                float nn = tanhf(accN1[mt][t][j] + bb.z + rr * (accN2[mt][t][j] + bb.w));
                float hold = h[row * CC + c];
                float v = (1.f - zz) * nn + zz * hold;
                if (relu) v = fmaxf(v, 0.f);
                h[row * CC + c] = v;
            }
        }
}

// ---------------- launch ----------------

extern "C" void kernel_launch(void* const* d_in, const int* in_sizes, int n_in,
                              void* d_out, int out_size, void* d_ws, size_t ws_size,
                              hipStream_t stream) {
    const float* x = (const float*)d_in[0];
    const int* ei = (const int*)d_in[1];
    const float* weights = (const float*)d_in[2];
    const float* w_ih = (const float*)d_in[3];
    const float* w_hh = (const float*)d_in[4];
    const float* b_ih = (const float*)d_in[5];
    const float* b_hh = (const float*)d_in[6];
    float* h = (float*)d_out;

    const int* src = ei;
    const int* dst = ei + NN_EDGES;

    // workspace carve
    float* mbuf = (float*)d_ws;                           // NN_PAD*128 fp32
    float* agg = mbuf + (size_t)NN_PAD * CC;              // NN_PAD*128 fp32
    float* bpack = agg + (size_t)NN_PAD * CC;             // NL*512
    float* endf = bpack + NL * 512;
    ushort* wm3 = (ushort*)endf;                          // 30*WM_LS
    ushort* gw3 = wm3 + (size_t)NL * NS * WM_LS;          // 6*GW_ML
    ushort* endu = gw3 + (size_t)6 * GW_ML;
    int* deg = (int*)endu;                                // 100000
    int* cursor = deg + NN_NODES;                         // 100000
    int* offsets = cursor + NN_NODES;                     // 100001
    int* csr = offsets + (NN_NODES + 1);                  // 600000
    int* partials = csr + NN_EDGES;                       // 99+

    hipMemcpyAsync(h, x, (size_t)NN_NODES * CC * sizeof(float),
                   hipMemcpyDeviceToDevice, stream);
    hipMemsetAsync(deg, 0, (size_t)2 * NN_NODES * sizeof(int), stream);

    const int EB = (NN_EDGES + 255) / 256;
    count_deg<<<EB, 256, 0, stream>>>(dst, deg);
    scan1<<<98, 256, 0, stream>>>(deg, offsets, partials);
    scan2<<<1, 128, 0, stream>>>(partials);
    scan3<<<98, 256, 0, stream>>>(offsets, partials);
    fill_csr<<<EB, 256, 0, stream>>>(src, dst, offsets, cursor, csr);
    pack_wm3<<<240, 256, 0, stream>>>(weights, wm3);
    pack_gw3<<<144, 256, 0, stream>>>(w_ih, w_hh, gw3);
    pack_bias_f32<<<6, 256, 0, stream>>>(b_ih, b_hh, bpack);

    const int GB32 = NN_NODES / 32;          // 3125 (exact)
    const int GB_GATH = NN_NODES / 8;        // 12500

    for (int l = 0; l < NL; l++) {
        for (int s = 0; s < NS; s++) {
            gemm_m_mfma<<<GB32, 256, 0, stream>>>(
                h, wm3 + (size_t)(l * NS + s) * WM_LS, mbuf);
            gather_agg<<<GB_GATH, 256, 0, stream>>>(mbuf, offsets, csr, agg);
            int relu = (s == NS - 1 && l < NL - 1) ? 1 : 0;
            gates_mfma<<<GB32, 256, 0, stream>>>(
                agg, h, gw3 + (size_t)l * GW_ML, gw3 + (size_t)(NL + l) * GW_ML,
                bpack + (size_t)l * 512, relu);
        }
    }
    (void)in_sizes; (void)n_in; (void)out_size; (void)ws_size;
}